// Round 1
// baseline (399.656 us; speedup 1.0000x reference)
//
#include <hip/hip_runtime.h>
#include <hip/hip_bf16.h>

#define TT 4096
#define CC 1024
#define NHEAD 16
#define DH 64
#define N3C 3072

typedef __attribute__((ext_vector_type(8))) short short8;
typedef __attribute__((ext_vector_type(4))) float floatx4;

__device__ __forceinline__ short f2bf(float f) {
    union { __hip_bfloat16 h; short s; } u;
    u.h = __float2bfloat16(f);
    return u.s;
}

// ---------------- convert x (fp32) -> bf16 ----------------
__global__ void k_cvt(const float* __restrict__ in, short* __restrict__ out, int n) {
    int i = (blockIdx.x * 256 + threadIdx.x) * 4;
    if (i < n) {
        float4 v = *(const float4*)&in[i];
        short4 r;
        r.x = f2bf(v.x); r.y = f2bf(v.y); r.z = f2bf(v.z); r.w = f2bf(v.w);
        *(short4*)&out[i] = r;
    }
}

// ---------------- transpose fp32 [K,N] -> bf16 [N,K] ----------------
__global__ void k_transpose(const float* __restrict__ in, short* __restrict__ out,
                            int K, int N) {
    __shared__ float tile[32][33];
    int nt = blockIdx.x * 32, kt = blockIdx.y * 32;
    int tx = threadIdx.x & 31, ty = threadIdx.x >> 5;   // ty in 0..7
#pragma unroll
    for (int i = 0; i < 32; i += 8)
        tile[ty + i][tx] = in[(size_t)(kt + ty + i) * N + nt + tx];
    __syncthreads();
#pragma unroll
    for (int i = 0; i < 32; i += 8)
        out[(size_t)(nt + ty + i) * K + kt + tx] = f2bf(tile[tx][ty + i]);
}

// ---------------- GEMM1: qkv = x @ w_qkv + b, scatter to Q/K/V [H,T,64] bf16 ----
// A: [M=4096, K=1024] bf16, Bt: [N=3072, K=1024] bf16
__global__ __launch_bounds__(256) void k_gemm_qkv(const short* __restrict__ A,
                                                  const short* __restrict__ Bt,
                                                  const float* __restrict__ bias,
                                                  short* __restrict__ Q,
                                                  short* __restrict__ Kb,
                                                  short* __restrict__ V) {
    const int m0 = blockIdx.y * 128;
    const int n0 = blockIdx.x * 128;
    __shared__ short As[128][40];
    __shared__ short Bs[128][40];
    const int tid = threadIdx.x;
    const int lane = tid & 63;
    const int w = tid >> 6;
    const int wm = w >> 1, wn = w & 1;
    const int quad = lane >> 4;
    const int l16 = lane & 15;
    floatx4 acc[4][4] = {};
    for (int kb = 0; kb < CC; kb += 32) {
#pragma unroll
        for (int it = 0; it < 2; ++it) {
            int L = tid + it * 256;      // 0..511
            int row = L >> 2;            // 4 x 8-elem loads per 32-wide row
            int col = (L & 3) * 8;
            *(short8*)&As[row][col] = *(const short8*)&A[(size_t)(m0 + row) * CC + kb + col];
            *(short8*)&Bs[row][col] = *(const short8*)&Bt[(size_t)(n0 + row) * CC + kb + col];
        }
        __syncthreads();
        short8 af[4], bf[4];
#pragma unroll
        for (int mi = 0; mi < 4; ++mi)
            af[mi] = *(const short8*)&As[wm * 64 + mi * 16 + l16][quad * 8];
#pragma unroll
        for (int ni = 0; ni < 4; ++ni)
            bf[ni] = *(const short8*)&Bs[wn * 64 + ni * 16 + l16][quad * 8];
#pragma unroll
        for (int mi = 0; mi < 4; ++mi)
#pragma unroll
            for (int ni = 0; ni < 4; ++ni)
                acc[mi][ni] = __builtin_amdgcn_mfma_f32_16x16x32_bf16(af[mi], bf[ni], acc[mi][ni], 0, 0, 0);
        __syncthreads();
    }
    // epilogue: scatter bf16 into [H, T, 64] per q/k/v
#pragma unroll
    for (int mi = 0; mi < 4; ++mi) {
#pragma unroll
        for (int ni = 0; ni < 4; ++ni) {
            int gm = m0 + wm * 64 + mi * 16 + quad * 4;
            int gn = n0 + wn * 64 + ni * 16 + l16;
            int which = gn >> 10;
            int cc = gn & 1023;
            int h = cc >> 6, d = cc & 63;
            short* dst = (which == 0) ? Q : ((which == 1) ? Kb : V);
            float bv = bias[gn];
#pragma unroll
            for (int r = 0; r < 4; ++r) {
                float v = acc[mi][ni][r] + bv;
                dst[((size_t)h * TT + (gm + r)) * DH + d] = f2bf(v);
            }
        }
    }
}

// ---------------- flash attention: per (q-tile of 64, head) ----------------
__global__ __launch_bounds__(256) void k_attn(const short* __restrict__ Qh,
                                              const short* __restrict__ Kh,
                                              const short* __restrict__ Vh,
                                              short* __restrict__ Ob) {
    const int h = blockIdx.y;
    const int qi = blockIdx.x;
    const int q0 = qi * 64;
    const int tid = threadIdx.x, lane = tid & 63, w = tid >> 6;
    const int quad = lane >> 4, l16 = lane & 15;
    __shared__ short Ks[64][72];
    __shared__ short Vt[64][72];   // transposed: [d][kk]
    __shared__ short Ps[64][72];
    const short* Qp = Qh + (size_t)h * TT * DH;
    const short* Kp = Kh + (size_t)h * TT * DH;
    const short* Vp = Vh + (size_t)h * TT * DH;

    short8 aq[2];
#pragma unroll
    for (int s = 0; s < 2; ++s)
        aq[s] = *(const short8*)&Qp[(size_t)(q0 + w * 16 + l16) * DH + s * 32 + quad * 8];

    floatx4 accO[4] = {};
    float m_i[4], l_i[4];
#pragma unroll
    for (int r = 0; r < 4; ++r) { m_i[r] = -1e30f; l_i[r] = 0.f; }

    for (int ki = 0; ki <= qi; ++ki) {
        const int k0 = ki * 64;
        __syncthreads();  // previous iteration's LDS reads done
        // stage K tile (coalesced)
#pragma unroll
        for (int it = 0; it < 2; ++it) {
            int L = tid + it * 256;
            int row = L >> 3;
            int col = (L & 7) * 8;
            *(short8*)&Ks[row][col] = *(const short8*)&Kp[(size_t)(k0 + row) * DH + col];
        }
        // stage V transposed (LDS-conflict-free lane mapping)
#pragma unroll
        for (int it = 0; it < 2; ++it) {
            int L = tid + it * 256;
            int vrow = L & 63;             // kk
            int vcol = (L >> 6) * 8;       // d
            short8 v = *(const short8*)&Vp[(size_t)(k0 + vrow) * DH + vcol];
#pragma unroll
            for (int j = 0; j < 8; ++j) Vt[vcol + j][vrow] = v[j];
        }
        __syncthreads();

        // S = Q K^T  (wave w: rows w*16..+16, cols 0..63)
        floatx4 accS[4] = {};
#pragma unroll
        for (int ni = 0; ni < 4; ++ni) {
#pragma unroll
            for (int s = 0; s < 2; ++s) {
                short8 bk = *(const short8*)&Ks[ni * 16 + l16][s * 32 + quad * 8];
                accS[ni] = __builtin_amdgcn_mfma_f32_16x16x32_bf16(aq[s], bk, accS[ni], 0, 0, 0);
            }
        }
        // scale + causal mask + row stats
        const bool diag = (ki == qi);
        float rowmax[4];
#pragma unroll
        for (int r = 0; r < 4; ++r) rowmax[r] = -1e30f;
#pragma unroll
        for (int ni = 0; ni < 4; ++ni) {
#pragma unroll
            for (int r = 0; r < 4; ++r) {
                float sv = accS[ni][r] * 0.125f;
                if (diag) {
                    int qrow = w * 16 + quad * 4 + r;
                    int kcol = ni * 16 + l16;
                    if (kcol > qrow) sv = -1e30f;
                }
                accS[ni][r] = sv;
                rowmax[r] = fmaxf(rowmax[r], sv);
            }
        }
#pragma unroll
        for (int off = 1; off < 16; off <<= 1)
#pragma unroll
            for (int r = 0; r < 4; ++r)
                rowmax[r] = fmaxf(rowmax[r], __shfl_xor(rowmax[r], off, 64));

        float alpha[4], psum[4];
#pragma unroll
        for (int r = 0; r < 4; ++r) {
            float mnew = fmaxf(m_i[r], rowmax[r]);
            alpha[r] = __expf(m_i[r] - mnew);
            m_i[r] = mnew;
            psum[r] = 0.f;
        }
#pragma unroll
        for (int ni = 0; ni < 4; ++ni) {
#pragma unroll
            for (int r = 0; r < 4; ++r) {
                float p = __expf(accS[ni][r] - m_i[r]);
                psum[r] += p;
                Ps[w * 16 + quad * 4 + r][ni * 16 + l16] = f2bf(p);
            }
        }
#pragma unroll
        for (int off = 1; off < 16; off <<= 1)
#pragma unroll
            for (int r = 0; r < 4; ++r)
                psum[r] += __shfl_xor(psum[r], off, 64);
#pragma unroll
        for (int r = 0; r < 4; ++r) l_i[r] = l_i[r] * alpha[r] + psum[r];
#pragma unroll
        for (int ni = 0; ni < 4; ++ni)
#pragma unroll
            for (int r = 0; r < 4; ++r) accO[ni][r] *= alpha[r];

        __syncthreads();  // P visible (also drains LDS writes)

        // O += P @ V   (A = P strip [16 x 64], B = V via Vt)
        short8 ap[2];
#pragma unroll
        for (int s = 0; s < 2; ++s)
            ap[s] = *(const short8*)&Ps[w * 16 + l16][s * 32 + quad * 8];
#pragma unroll
        for (int ni = 0; ni < 4; ++ni) {
#pragma unroll
            for (int s = 0; s < 2; ++s) {
                short8 bv = *(const short8*)&Vt[ni * 16 + l16][s * 32 + quad * 8];
                accO[ni] = __builtin_amdgcn_mfma_f32_16x16x32_bf16(ap[s], bv, accO[ni], 0, 0, 0);
            }
        }
    }
    // epilogue: O / l -> Ob [T, C] bf16 (col = h*64 + d)
#pragma unroll
    for (int ni = 0; ni < 4; ++ni) {
#pragma unroll
        for (int r = 0; r < 4; ++r) {
            float o = accO[ni][r] / l_i[r];
            int t = q0 + w * 16 + quad * 4 + r;
            int d = ni * 16 + l16;
            Ob[(size_t)t * CC + h * DH + d] = f2bf(o);
        }
    }
}

// ---------------- GEMM2: out = Ob @ w_proj + b (fp32 out) ----------------
// A: [4096, 1024] bf16, Bt: [1024, 1024] bf16
__global__ __launch_bounds__(256) void k_gemm_proj(const short* __restrict__ A,
                                                   const short* __restrict__ Bt,
                                                   const float* __restrict__ bias,
                                                   float* __restrict__ out) {
    const int m0 = blockIdx.y * 128;
    const int n0 = blockIdx.x * 128;
    __shared__ short As[128][40];
    __shared__ short Bs[128][40];
    const int tid = threadIdx.x;
    const int lane = tid & 63;
    const int w = tid >> 6;
    const int wm = w >> 1, wn = w & 1;
    const int quad = lane >> 4;
    const int l16 = lane & 15;
    floatx4 acc[4][4] = {};
    for (int kb = 0; kb < CC; kb += 32) {
#pragma unroll
        for (int it = 0; it < 2; ++it) {
            int L = tid + it * 256;
            int row = L >> 2;
            int col = (L & 3) * 8;
            *(short8*)&As[row][col] = *(const short8*)&A[(size_t)(m0 + row) * CC + kb + col];
            *(short8*)&Bs[row][col] = *(const short8*)&Bt[(size_t)(n0 + row) * CC + kb + col];
        }
        __syncthreads();
        short8 af[4], bf[4];
#pragma unroll
        for (int mi = 0; mi < 4; ++mi)
            af[mi] = *(const short8*)&As[wm * 64 + mi * 16 + l16][quad * 8];
#pragma unroll
        for (int ni = 0; ni < 4; ++ni)
            bf[ni] = *(const short8*)&Bs[wn * 64 + ni * 16 + l16][quad * 8];
#pragma unroll
        for (int mi = 0; mi < 4; ++mi)
#pragma unroll
            for (int ni = 0; ni < 4; ++ni)
                acc[mi][ni] = __builtin_amdgcn_mfma_f32_16x16x32_bf16(af[mi], bf[ni], acc[mi][ni], 0, 0, 0);
        __syncthreads();
    }
#pragma unroll
    for (int mi = 0; mi < 4; ++mi) {
#pragma unroll
        for (int ni = 0; ni < 4; ++ni) {
            int gm = m0 + wm * 64 + mi * 16 + quad * 4;
            int gn = n0 + wn * 64 + ni * 16 + l16;
            float bv = bias[gn];
#pragma unroll
            for (int r = 0; r < 4; ++r)
                out[(size_t)(gm + r) * CC + gn] = acc[mi][ni][r] + bv;
        }
    }
}

extern "C" void kernel_launch(void* const* d_in, const int* in_sizes, int n_in,
                              void* d_out, int out_size, void* d_ws, size_t ws_size,
                              hipStream_t stream) {
    const float* x      = (const float*)d_in[0];
    const float* w_qkv  = (const float*)d_in[1];
    const float* b_qkv  = (const float*)d_in[2];
    const float* w_proj = (const float*)d_in[3];
    const float* b_proj = (const float*)d_in[4];
    float* out = (float*)d_out;
    char* ws = (char*)d_ws;

    // workspace layout (bytes)
    short* xb     = (short*)(ws);                       // 4096*1024*2 = 8388608
    short* wqkvT  = (short*)(ws + 8388608);             // 3072*1024*2 = 6291456
    short* wprojT = (short*)(ws + 14680064);            // 1024*1024*2 = 2097152
    short* Qh     = (short*)(ws + 16777216);            // 16*4096*64*2 = 8388608
    short* Kh     = (short*)(ws + 25165824);
    short* Vh     = (short*)(ws + 33554432);
    short* Ob     = (short*)(ws + 41943040);            // 4096*1024*2
    // total 50331648 bytes (48 MB)

    k_cvt<<<4096, 256, 0, stream>>>(x, xb, TT * CC);
    k_transpose<<<dim3(N3C / 32, CC / 32), 256, 0, stream>>>(w_qkv, wqkvT, CC, N3C);
    k_transpose<<<dim3(CC / 32, CC / 32), 256, 0, stream>>>(w_proj, wprojT, CC, CC);
    k_gemm_qkv<<<dim3(N3C / 128, TT / 128), 256, 0, stream>>>(xb, wqkvT, b_qkv, Qh, Kh, Vh);
    k_attn<<<dim3(TT / 64, NHEAD), 256, 0, stream>>>(Qh, Kh, Vh, Ob);
    k_gemm_proj<<<dim3(CC / 128, TT / 128), 256, 0, stream>>>(Ob, wprojT, b_proj, out);
}

// Round 2
// 271.103 us; speedup vs baseline: 1.4742x; 1.4742x over previous
//
#include <hip/hip_runtime.h>
#include <hip/hip_bf16.h>

#define TT 4096
#define CC 1024
#define NHEAD 16
#define DH 64
#define N3C 3072

typedef __attribute__((ext_vector_type(8))) short short8;
typedef __attribute__((ext_vector_type(4))) float floatx4;

// Q pre-scale: 1/sqrt(64) * log2(e)  (softmax done in exp2 domain)
#define QSCALE 0.18033688011112042f

__device__ __forceinline__ short f2bf(float f) {
    union { __hip_bfloat16 h; short s; } u;
    u.h = __float2bfloat16(f);
    return u.s;
}

// ---------------- convert x (fp32) -> bf16 ----------------
__global__ void k_cvt(const float* __restrict__ in, short* __restrict__ out, int n) {
    int i = (blockIdx.x * 256 + threadIdx.x) * 4;
    if (i < n) {
        float4 v = *(const float4*)&in[i];
        short4 r;
        r.x = f2bf(v.x); r.y = f2bf(v.y); r.z = f2bf(v.z); r.w = f2bf(v.w);
        *(short4*)&out[i] = r;
    }
}

// ---------------- transpose fp32 [K,N] -> bf16 [N,K] ----------------
__global__ void k_transpose(const float* __restrict__ in, short* __restrict__ out,
                            int K, int N) {
    __shared__ float tile[32][33];
    int nt = blockIdx.x * 32, kt = blockIdx.y * 32;
    int tx = threadIdx.x & 31, ty = threadIdx.x >> 5;
#pragma unroll
    for (int i = 0; i < 32; i += 8)
        tile[ty + i][tx] = in[(size_t)(kt + ty + i) * N + nt + tx];
    __syncthreads();
#pragma unroll
    for (int i = 0; i < 32; i += 8)
        out[(size_t)(nt + ty + i) * K + kt + tx] = f2bf(tile[tx][ty + i]);
}

// ---------------- GEMM1: qkv = x @ w_qkv + b ----------------
// Q -> [H,T,64] bf16, pre-scaled by QSCALE
// K -> [H,T,64] bf16
// V -> transposed [H,64,T] bf16 (so attention can stage V^T with b128 LDS writes)
__global__ __launch_bounds__(256) void k_gemm_qkv(const short* __restrict__ A,
                                                  const short* __restrict__ Bt,
                                                  const float* __restrict__ bias,
                                                  short* __restrict__ Q,
                                                  short* __restrict__ Kb,
                                                  short* __restrict__ Vtg) {
    const int m0 = blockIdx.y * 128;
    const int n0 = blockIdx.x * 128;
    __shared__ short As[128][40];
    __shared__ short Bs[128][40];
    const int tid = threadIdx.x;
    const int lane = tid & 63;
    const int w = tid >> 6;
    const int wm = w >> 1, wn = w & 1;
    const int quad = lane >> 4;
    const int l16 = lane & 15;
    floatx4 acc[4][4] = {};
    for (int kb = 0; kb < CC; kb += 32) {
#pragma unroll
        for (int it = 0; it < 2; ++it) {
            int L = tid + it * 256;
            int row = L >> 2;
            int col = (L & 3) * 8;
            *(short8*)&As[row][col] = *(const short8*)&A[(size_t)(m0 + row) * CC + kb + col];
            *(short8*)&Bs[row][col] = *(const short8*)&Bt[(size_t)(n0 + row) * CC + kb + col];
        }
        __syncthreads();
        short8 af[4], bf[4];
#pragma unroll
        for (int mi = 0; mi < 4; ++mi)
            af[mi] = *(const short8*)&As[wm * 64 + mi * 16 + l16][quad * 8];
#pragma unroll
        for (int ni = 0; ni < 4; ++ni)
            bf[ni] = *(const short8*)&Bs[wn * 64 + ni * 16 + l16][quad * 8];
#pragma unroll
        for (int mi = 0; mi < 4; ++mi)
#pragma unroll
            for (int ni = 0; ni < 4; ++ni)
                acc[mi][ni] = __builtin_amdgcn_mfma_f32_16x16x32_bf16(af[mi], bf[ni], acc[mi][ni], 0, 0, 0);
        __syncthreads();
    }
#pragma unroll
    for (int mi = 0; mi < 4; ++mi) {
#pragma unroll
        for (int ni = 0; ni < 4; ++ni) {
            int gm = m0 + wm * 64 + mi * 16 + quad * 4;
            int gn = n0 + wn * 64 + ni * 16 + l16;
            int which = gn >> 10;
            int cc = gn & 1023;
            int h = cc >> 6, d = cc & 63;
            float bv = bias[gn];
            if (which == 0) {          // Q: [H,T,64], pre-scaled
#pragma unroll
                for (int r = 0; r < 4; ++r) {
                    float v = (acc[mi][ni][r] + bv) * QSCALE;
                    Q[((size_t)h * TT + (gm + r)) * DH + d] = f2bf(v);
                }
            } else if (which == 1) {   // K: [H,T,64]
#pragma unroll
                for (int r = 0; r < 4; ++r) {
                    float v = acc[mi][ni][r] + bv;
                    Kb[((size_t)h * TT + (gm + r)) * DH + d] = f2bf(v);
                }
            } else {                   // V^T: [H,64,T], 4 consecutive t -> short4
                short4 vv;
                vv.x = f2bf(acc[mi][ni][0] + bv);
                vv.y = f2bf(acc[mi][ni][1] + bv);
                vv.z = f2bf(acc[mi][ni][2] + bv);
                vv.w = f2bf(acc[mi][ni][3] + bv);
                *(short4*)&Vtg[((size_t)h * DH + d) * TT + gm] = vv;
            }
        }
    }
}

// ---------------- flash attention, work-balanced ----------------
// Block (pair, h) processes q-tiles qi=pair and qi=63-pair: 65 k-iterations each.
__global__ __launch_bounds__(256) void k_attn(const short* __restrict__ Qh,
                                              const short* __restrict__ Kh,
                                              const short* __restrict__ VhT,
                                              short* __restrict__ Ob) {
    const int h = blockIdx.y;
    const int pair = blockIdx.x;    // 0..31
    const int tid = threadIdx.x, lane = tid & 63, w = tid >> 6;
    const int quad = lane >> 4, l16 = lane & 15;
    __shared__ short Ks[64][72];
    __shared__ short Vt[64][72];    // [d][kk]
    __shared__ short Ps[64][72];
    const short* Qp = Qh + (size_t)h * TT * DH;
    const short* Kp = Kh + (size_t)h * TT * DH;
    const short* Vp = VhT + (size_t)h * DH * TT;   // [d][t]

    short8 onesB;
#pragma unroll
    for (int j = 0; j < 8; ++j) onesB[j] = (short)0x3F80;  // bf16 1.0

#pragma unroll 1
    for (int half = 0; half < 2; ++half) {
        const int qi = half ? (63 - pair) : pair;
        const int q0 = qi * 64;

        short8 aq[2];
#pragma unroll
        for (int s = 0; s < 2; ++s)
            aq[s] = *(const short8*)&Qp[(size_t)(q0 + w * 16 + l16) * DH + s * 32 + quad * 8];

        floatx4 accO[4] = {};
        floatx4 accL = {};
        float m_i[4];
#pragma unroll
        for (int r = 0; r < 4; ++r) m_i[r] = -1e30f;

        for (int ki = 0; ki <= qi; ++ki) {
            const int k0 = ki * 64;
            __syncthreads();   // prior iteration's (or half's) LDS reads done
#pragma unroll
            for (int it = 0; it < 2; ++it) {
                int L = tid + it * 256;
                int row = L >> 3;
                int col = (L & 7) * 8;
                *(short8*)&Ks[row][col] = *(const short8*)&Kp[(size_t)(k0 + row) * DH + col];
                *(short8*)&Vt[row][col] = *(const short8*)&Vp[(size_t)row * TT + k0 + col];
            }
            __syncthreads();

            // S = Q K^T (pre-scaled, exp2 domain)
            floatx4 accS[4] = {};
#pragma unroll
            for (int ni = 0; ni < 4; ++ni) {
#pragma unroll
                for (int s = 0; s < 2; ++s) {
                    short8 bk = *(const short8*)&Ks[ni * 16 + l16][s * 32 + quad * 8];
                    accS[ni] = __builtin_amdgcn_mfma_f32_16x16x32_bf16(aq[s], bk, accS[ni], 0, 0, 0);
                }
            }
            const bool diag = (ki == qi);
            float rowmax[4];
#pragma unroll
            for (int r = 0; r < 4; ++r) rowmax[r] = -1e30f;
#pragma unroll
            for (int ni = 0; ni < 4; ++ni) {
#pragma unroll
                for (int r = 0; r < 4; ++r) {
                    float sv = accS[ni][r];
                    if (diag) {
                        int qrow = w * 16 + quad * 4 + r;
                        int kcol = ni * 16 + l16;
                        if (kcol > qrow) sv = -1e30f;
                    }
                    accS[ni][r] = sv;
                    rowmax[r] = fmaxf(rowmax[r], sv);
                }
            }
#pragma unroll
            for (int off = 1; off < 16; off <<= 1)
#pragma unroll
                for (int r = 0; r < 4; ++r)
                    rowmax[r] = fmaxf(rowmax[r], __shfl_xor(rowmax[r], off, 64));

            float alpha[4];
#pragma unroll
            for (int r = 0; r < 4; ++r) {
                float mnew = fmaxf(m_i[r], rowmax[r]);
                alpha[r] = __builtin_amdgcn_exp2f(m_i[r] - mnew);
                m_i[r] = mnew;
            }
#pragma unroll
            for (int ni = 0; ni < 4; ++ni)
#pragma unroll
                for (int r = 0; r < 4; ++r) {
                    float p = __builtin_amdgcn_exp2f(accS[ni][r] - m_i[r]);
                    Ps[w * 16 + quad * 4 + r][ni * 16 + l16] = f2bf(p);
                }
#pragma unroll
            for (int ni = 0; ni < 4; ++ni)
#pragma unroll
                for (int r = 0; r < 4; ++r) accO[ni][r] *= alpha[r];
#pragma unroll
            for (int r = 0; r < 4; ++r) accL[r] *= alpha[r];

            __syncthreads();   // P visible

            short8 ap[2];
#pragma unroll
            for (int s = 0; s < 2; ++s)
                ap[s] = *(const short8*)&Ps[w * 16 + l16][s * 32 + quad * 8];
#pragma unroll
            for (int ni = 0; ni < 4; ++ni) {
#pragma unroll
                for (int s = 0; s < 2; ++s) {
                    short8 bv = *(const short8*)&Vt[ni * 16 + l16][s * 32 + quad * 8];
                    accO[ni] = __builtin_amdgcn_mfma_f32_16x16x32_bf16(ap[s], bv, accO[ni], 0, 0, 0);
                }
            }
#pragma unroll
            for (int s = 0; s < 2; ++s)
                accL = __builtin_amdgcn_mfma_f32_16x16x32_bf16(ap[s], onesB, accL, 0, 0, 0);
        }
        // epilogue: O / l -> Ob [T, C] bf16
#pragma unroll
        for (int ni = 0; ni < 4; ++ni) {
#pragma unroll
            for (int r = 0; r < 4; ++r) {
                float o = accO[ni][r] / accL[r];
                int t = q0 + w * 16 + quad * 4 + r;
                int d = ni * 16 + l16;
                Ob[(size_t)t * CC + h * DH + d] = f2bf(o);
            }
        }
    }
}

// ---------------- GEMM2: out = Ob @ w_proj + b (fp32 out) ----------------
__global__ __launch_bounds__(256) void k_gemm_proj(const short* __restrict__ A,
                                                   const short* __restrict__ Bt,
                                                   const float* __restrict__ bias,
                                                   float* __restrict__ out) {
    const int m0 = blockIdx.y * 128;
    const int n0 = blockIdx.x * 128;
    __shared__ short As[128][40];
    __shared__ short Bs[128][40];
    const int tid = threadIdx.x;
    const int lane = tid & 63;
    const int w = tid >> 6;
    const int wm = w >> 1, wn = w & 1;
    const int quad = lane >> 4;
    const int l16 = lane & 15;
    floatx4 acc[4][4] = {};
    for (int kb = 0; kb < CC; kb += 32) {
#pragma unroll
        for (int it = 0; it < 2; ++it) {
            int L = tid + it * 256;
            int row = L >> 2;
            int col = (L & 3) * 8;
            *(short8*)&As[row][col] = *(const short8*)&A[(size_t)(m0 + row) * CC + kb + col];
            *(short8*)&Bs[row][col] = *(const short8*)&Bt[(size_t)(n0 + row) * CC + kb + col];
        }
        __syncthreads();
        short8 af[4], bf[4];
#pragma unroll
        for (int mi = 0; mi < 4; ++mi)
            af[mi] = *(const short8*)&As[wm * 64 + mi * 16 + l16][quad * 8];
#pragma unroll
        for (int ni = 0; ni < 4; ++ni)
            bf[ni] = *(const short8*)&Bs[wn * 64 + ni * 16 + l16][quad * 8];
#pragma unroll
        for (int mi = 0; mi < 4; ++mi)
#pragma unroll
            for (int ni = 0; ni < 4; ++ni)
                acc[mi][ni] = __builtin_amdgcn_mfma_f32_16x16x32_bf16(af[mi], bf[ni], acc[mi][ni], 0, 0, 0);
        __syncthreads();
    }
#pragma unroll
    for (int mi = 0; mi < 4; ++mi) {
#pragma unroll
        for (int ni = 0; ni < 4; ++ni) {
            int gm = m0 + wm * 64 + mi * 16 + quad * 4;
            int gn = n0 + wn * 64 + ni * 16 + l16;
            float bv = bias[gn];
#pragma unroll
            for (int r = 0; r < 4; ++r)
                out[(size_t)(gm + r) * CC + gn] = acc[mi][ni][r] + bv;
        }
    }
}

extern "C" void kernel_launch(void* const* d_in, const int* in_sizes, int n_in,
                              void* d_out, int out_size, void* d_ws, size_t ws_size,
                              hipStream_t stream) {
    const float* x      = (const float*)d_in[0];
    const float* w_qkv  = (const float*)d_in[1];
    const float* b_qkv  = (const float*)d_in[2];
    const float* w_proj = (const float*)d_in[3];
    const float* b_proj = (const float*)d_in[4];
    float* out = (float*)d_out;
    char* ws = (char*)d_ws;

    short* xb     = (short*)(ws);                       // 8388608 B
    short* wqkvT  = (short*)(ws + 8388608);             // 6291456 B
    short* wprojT = (short*)(ws + 14680064);            // 2097152 B
    short* Qh     = (short*)(ws + 16777216);            // 8388608 B
    short* Kh     = (short*)(ws + 25165824);
    short* VhT    = (short*)(ws + 33554432);            // [H,64,T]
    short* Ob     = (short*)(ws + 41943040);
    // total 50331648 B (48 MB)

    k_cvt<<<4096, 256, 0, stream>>>(x, xb, TT * CC);
    k_transpose<<<dim3(N3C / 32, CC / 32), 256, 0, stream>>>(w_qkv, wqkvT, CC, N3C);
    k_transpose<<<dim3(CC / 32, CC / 32), 256, 0, stream>>>(w_proj, wprojT, CC, CC);
    k_gemm_qkv<<<dim3(N3C / 128, TT / 128), 256, 0, stream>>>(xb, wqkvT, b_qkv, Qh, Kh, VhT);
    k_attn<<<dim3(32, NHEAD), 256, 0, stream>>>(Qh, Kh, VhT, Ob);
    k_gemm_proj<<<dim3(CC / 128, TT / 128), 256, 0, stream>>>(Ob, wprojT, b_proj, out);
}

// Round 3
// 225.601 us; speedup vs baseline: 1.7715x; 1.2017x over previous
//
#include <hip/hip_runtime.h>
#include <hip/hip_bf16.h>

#define TT 4096
#define CC 1024
#define NHEAD 16
#define DH 64
#define N3C 3072

typedef __attribute__((ext_vector_type(8))) short short8;
typedef __attribute__((ext_vector_type(4))) float floatx4;

// Q pre-scale: 1/sqrt(64) * log2(e)  (softmax in exp2 domain)
#define QSCALE 0.18033688011112042f

__device__ __forceinline__ short f2bf(float f) {
    union { __hip_bfloat16 h; short s; } u;
    u.h = __float2bfloat16(f);
    return u.s;
}

// async global->LDS 16B per lane; LDS dest = wave-uniform base + lane*16
__device__ __forceinline__ void gload_lds16(const void* g, void* l) {
    __builtin_amdgcn_global_load_lds(
        (const __attribute__((address_space(1))) unsigned int*)(unsigned long long)g,
        (__attribute__((address_space(3))) unsigned int*)(unsigned int)(unsigned long long)l,
        16, 0, 0);
}

// pack two fp32 -> bf16x2 by truncation (1 v_perm)
__device__ __forceinline__ unsigned pk_trunc(float lo, float hi) {
    return __builtin_amdgcn_perm(__float_as_uint(hi), __float_as_uint(lo), 0x07060302u);
}

// ---------------- convert x (fp32) -> bf16 ----------------
__global__ void k_cvt(const float* __restrict__ in, short* __restrict__ out, int n) {
    int i = (blockIdx.x * 256 + threadIdx.x) * 4;
    if (i < n) {
        float4 v = *(const float4*)&in[i];
        short4 r;
        r.x = f2bf(v.x); r.y = f2bf(v.y); r.z = f2bf(v.z); r.w = f2bf(v.w);
        *(short4*)&out[i] = r;
    }
}

// ---------------- transpose fp32 [K,N] -> bf16 [N,K] ----------------
__global__ void k_transpose(const float* __restrict__ in, short* __restrict__ out,
                            int K, int N) {
    __shared__ float tile[32][33];
    int nt = blockIdx.x * 32, kt = blockIdx.y * 32;
    int tx = threadIdx.x & 31, ty = threadIdx.x >> 5;
#pragma unroll
    for (int i = 0; i < 32; i += 8)
        tile[ty + i][tx] = in[(size_t)(kt + ty + i) * N + nt + tx];
    __syncthreads();
#pragma unroll
    for (int i = 0; i < 32; i += 8)
        out[(size_t)(nt + ty + i) * K + kt + tx] = f2bf(tile[tx][ty + i]);
}

// ---------------- GEMM1: qkv = x @ w_qkv + b ----------------
// Q -> [H,T,64] pre-scaled; K -> [H,T,64]; V -> [H,64,T] (transposed)
__global__ __launch_bounds__(256) void k_gemm_qkv(const short* __restrict__ A,
                                                  const short* __restrict__ Bt,
                                                  const float* __restrict__ bias,
                                                  short* __restrict__ Q,
                                                  short* __restrict__ Kb,
                                                  short* __restrict__ Vtg) {
    const int m0 = blockIdx.y * 128;
    const int n0 = blockIdx.x * 128;
    __shared__ __attribute__((aligned(16))) short As[128 * 32];
    __shared__ __attribute__((aligned(16))) short Bs[128 * 32];
    const int tid = threadIdx.x;
    const int lane = tid & 63;
    const int w = tid >> 6;
    const int wm = w >> 1, wn = w & 1;
    const int quad = lane >> 4;
    const int l16 = lane & 15;

    // staging: Bx = it*256 + tid; row = Bx>>2, col8 = (Bx&3)*8
    const int r0 = tid >> 2, c0 = (tid & 3) * 8;
    const short* pA0 = A + (size_t)(m0 + r0) * CC + c0;
    const short* pA1 = pA0 + (size_t)64 * CC;
    const short* pB0 = Bt + (size_t)(n0 + r0) * CC + c0;
    const short* pB1 = pB0 + (size_t)64 * CC;
    short* lA0 = &As[(w * 64) * 8];
    short* lA1 = &As[(256 + w * 64) * 8];
    short* lB0 = &Bs[(w * 64) * 8];
    short* lB1 = &Bs[(256 + w * 64) * 8];

    floatx4 acc[4][4] = {};
    for (int kb = 0; kb < CC; kb += 32) {
        __syncthreads();
        gload_lds16(pA0 + kb, lA0);
        gload_lds16(pA1 + kb, lA1);
        gload_lds16(pB0 + kb, lB0);
        gload_lds16(pB1 + kb, lB1);
        __syncthreads();
        short8 af[4], bf[4];
#pragma unroll
        for (int mi = 0; mi < 4; ++mi)
            af[mi] = *(const short8*)&As[(wm * 64 + mi * 16 + l16) * 32 + quad * 8];
#pragma unroll
        for (int ni = 0; ni < 4; ++ni)
            bf[ni] = *(const short8*)&Bs[(wn * 64 + ni * 16 + l16) * 32 + quad * 8];
#pragma unroll
        for (int mi = 0; mi < 4; ++mi)
#pragma unroll
            for (int ni = 0; ni < 4; ++ni)
                acc[mi][ni] = __builtin_amdgcn_mfma_f32_16x16x32_bf16(af[mi], bf[ni], acc[mi][ni], 0, 0, 0);
    }
#pragma unroll
    for (int mi = 0; mi < 4; ++mi) {
#pragma unroll
        for (int ni = 0; ni < 4; ++ni) {
            int gm = m0 + wm * 64 + mi * 16 + quad * 4;
            int gn = n0 + wn * 64 + ni * 16 + l16;
            int which = gn >> 10;
            int cc = gn & 1023;
            int h = cc >> 6, d = cc & 63;
            float bv = bias[gn];
            if (which == 0) {
#pragma unroll
                for (int r = 0; r < 4; ++r) {
                    float v = (acc[mi][ni][r] + bv) * QSCALE;
                    Q[((size_t)h * TT + (gm + r)) * DH + d] = f2bf(v);
                }
            } else if (which == 1) {
#pragma unroll
                for (int r = 0; r < 4; ++r) {
                    float v = acc[mi][ni][r] + bv;
                    Kb[((size_t)h * TT + (gm + r)) * DH + d] = f2bf(v);
                }
            } else {
                short4 vv;
                vv.x = f2bf(acc[mi][ni][0] + bv);
                vv.y = f2bf(acc[mi][ni][1] + bv);
                vv.z = f2bf(acc[mi][ni][2] + bv);
                vv.w = f2bf(acc[mi][ni][3] + bv);
                *(short4*)&Vtg[((size_t)h * DH + d) * TT + gm] = vv;
            }
        }
    }
}

// ---------------- flash attention v2 ----------------
// S^T trick (A=K,B=Q), m=0 fixed (exp2-domain scores bounded ~8), BK=128,
// global_load_lds staging with XOR-swizzled 16B blocks.
__global__ __launch_bounds__(256) void k_attn(const short* __restrict__ Qh,
                                              const short* __restrict__ Kh,
                                              const short* __restrict__ VhT,
                                              short* __restrict__ Ob) {
    const int h = blockIdx.y;
    const int pair = blockIdx.x;    // 0..31
    const int tid = threadIdx.x, lane = tid & 63, w = tid >> 6;
    const int quad = lane >> 4, l16 = lane & 15;

    __shared__ __attribute__((aligned(16))) short Ks[128 * 64];   // [k][d], swizzled
    __shared__ __attribute__((aligned(16))) short Vt[64 * 128];   // [d][k], swizzled
    __shared__ __attribute__((aligned(16))) short Ps[4 * 16 * 136]; // per-wave [q16][136]

    const short* Qp = Qh + (size_t)h * TT * DH;
    const short* Kp = Kh + (size_t)h * TT * DH;
    const short* Vp = VhT + (size_t)h * DH * TT;
    short* PSw = &Ps[w * 16 * 136];

    // staging address precompute (constant across k-iters)
    const short* pK[4]; const short* pV[4];
    short* lK[4]; short* lV[4];
#pragma unroll
    for (int it = 0; it < 4; ++it) {
        int Bx = it * 256 + tid;
        int r = Bx >> 3;
        int b = (Bx & 7) ^ (r & 7);
        pK[it] = Kp + (size_t)r * DH + b * 8;
        lK[it] = &Ks[(it * 256 + w * 64) * 8];
        int d = Bx >> 4;
        int cb = Bx & 15;
        int c = (cb & 8) | ((cb ^ d) & 7);
        pV[it] = Vp + (size_t)d * TT + c * 8;
        lV[it] = &Vt[(it * 256 + w * 64) * 8];
    }
    // fragment read offsets (swizzle-aware)
    int koff[2], voff[4];
#pragma unroll
    for (int s = 0; s < 2; ++s)
        koff[s] = l16 * 64 + ((4 * s + quad) ^ (l16 & 7)) * 8;
#pragma unroll
    for (int ks = 0; ks < 4; ++ks)
        voff[ks] = l16 * 128 + ((8 * (ks >> 1)) | ((4 * (ks & 1) + quad) ^ (l16 & 7))) * 8;

#pragma unroll 1
    for (int half = 0; half < 2; ++half) {
        const int qi = half ? (63 - pair) : pair;
        const int q0 = qi * 64;
        const int nk = (qi >> 1) + 1;
        const int qv = q0 + w * 16 + l16;

        short8 aq[2];
#pragma unroll
        for (int s = 0; s < 2; ++s)
            aq[s] = *(const short8*)&Qp[(size_t)(q0 + w * 16 + l16) * DH + s * 32 + quad * 8];

        floatx4 accO[4] = {};
        float l_part = 0.f;

        auto kstep = [&](int k0, bool masked) {
            __syncthreads();   // buffer reuse guard
#pragma unroll
            for (int it = 0; it < 4; ++it) {
                gload_lds16(pK[it] + (size_t)k0 * DH, lK[it]);
                gload_lds16(pV[it] + k0, lV[it]);
            }
            __syncthreads();   // staging visible

            // S^T = K Q^T : D[k][q], lane holds k = mi*16+quad*4+r, q = l16
            floatx4 accS[8] = {};
#pragma unroll
            for (int mi = 0; mi < 8; ++mi) {
#pragma unroll
                for (int s = 0; s < 2; ++s) {
                    short8 ak = *(const short8*)&Ks[mi * 1024 + koff[s]];
                    accS[mi] = __builtin_amdgcn_mfma_f32_16x16x32_bf16(ak, aq[s], accS[mi], 0, 0, 0);
                }
            }
            // softmax (m=0): p = exp2(s), masked -> 0; pack -> Ps b64 writes
            const int kg_base = k0 + quad * 4;
#pragma unroll
            for (int mi = 0; mi < 8; ++mi) {
                float p[4];
#pragma unroll
                for (int r = 0; r < 4; ++r) {
                    float e = __builtin_amdgcn_exp2f(accS[mi][r]);
                    if (masked) {
                        int kg = kg_base + mi * 16 + r;
                        e = (kg <= qv) ? e : 0.f;
                    }
                    p[r] = e;
                    l_part += e;
                }
                uint2 pk;
                pk.x = pk_trunc(p[0], p[1]);
                pk.y = pk_trunc(p[2], p[3]);
                *(uint2*)&PSw[l16 * 136 + mi * 16 + quad * 4] = pk;
            }
            // O += P V : D[q][d], A = P frags, B = V frags
#pragma unroll
            for (int ks = 0; ks < 4; ++ks) {
                short8 ap = *(const short8*)&PSw[l16 * 136 + ks * 32 + quad * 8];
#pragma unroll
                for (int ni = 0; ni < 4; ++ni) {
                    short8 bv = *(const short8*)&Vt[ni * 2048 + voff[ks]];
                    accO[ni] = __builtin_amdgcn_mfma_f32_16x16x32_bf16(ap, bv, accO[ni], 0, 0, 0);
                }
            }
        };

        for (int ki = 0; ki < nk - 1; ++ki) kstep(ki * 128, false);
        kstep((nk - 1) * 128, true);

        // reduce l across quads (lane's l is for q = l16)
        l_part += __shfl_xor(l_part, 16, 64);
        l_part += __shfl_xor(l_part, 32, 64);
        // broadcast l to O rows (O row q = quad*4+r)
        float lr[4];
#pragma unroll
        for (int r = 0; r < 4; ++r)
            lr[r] = __shfl(l_part, quad * 4 + r, 64);
#pragma unroll
        for (int ni = 0; ni < 4; ++ni) {
#pragma unroll
            for (int r = 0; r < 4; ++r) {
                float o = accO[ni][r] / lr[r];
                int t = q0 + w * 16 + quad * 4 + r;
                int d = ni * 16 + l16;
                Ob[(size_t)t * CC + h * DH + d] = f2bf(o);
            }
        }
    }
}

// ---------------- GEMM2: out = Ob @ w_proj + b (fp32 out) ----------------
__global__ __launch_bounds__(256) void k_gemm_proj(const short* __restrict__ A,
                                                   const short* __restrict__ Bt,
                                                   const float* __restrict__ bias,
                                                   float* __restrict__ out) {
    const int m0 = blockIdx.y * 128;
    const int n0 = blockIdx.x * 128;
    __shared__ __attribute__((aligned(16))) short As[128 * 32];
    __shared__ __attribute__((aligned(16))) short Bs[128 * 32];
    const int tid = threadIdx.x;
    const int lane = tid & 63;
    const int w = tid >> 6;
    const int wm = w >> 1, wn = w & 1;
    const int quad = lane >> 4;
    const int l16 = lane & 15;

    const int r0 = tid >> 2, c0 = (tid & 3) * 8;
    const short* pA0 = A + (size_t)(m0 + r0) * CC + c0;
    const short* pA1 = pA0 + (size_t)64 * CC;
    const short* pB0 = Bt + (size_t)(n0 + r0) * CC + c0;
    const short* pB1 = pB0 + (size_t)64 * CC;
    short* lA0 = &As[(w * 64) * 8];
    short* lA1 = &As[(256 + w * 64) * 8];
    short* lB0 = &Bs[(w * 64) * 8];
    short* lB1 = &Bs[(256 + w * 64) * 8];

    floatx4 acc[4][4] = {};
    for (int kb = 0; kb < CC; kb += 32) {
        __syncthreads();
        gload_lds16(pA0 + kb, lA0);
        gload_lds16(pA1 + kb, lA1);
        gload_lds16(pB0 + kb, lB0);
        gload_lds16(pB1 + kb, lB1);
        __syncthreads();
        short8 af[4], bf[4];
#pragma unroll
        for (int mi = 0; mi < 4; ++mi)
            af[mi] = *(const short8*)&As[(wm * 64 + mi * 16 + l16) * 32 + quad * 8];
#pragma unroll
        for (int ni = 0; ni < 4; ++ni)
            bf[ni] = *(const short8*)&Bs[(wn * 64 + ni * 16 + l16) * 32 + quad * 8];
#pragma unroll
        for (int mi = 0; mi < 4; ++mi)
#pragma unroll
            for (int ni = 0; ni < 4; ++ni)
                acc[mi][ni] = __builtin_amdgcn_mfma_f32_16x16x32_bf16(af[mi], bf[ni], acc[mi][ni], 0, 0, 0);
    }
#pragma unroll
    for (int mi = 0; mi < 4; ++mi) {
#pragma unroll
        for (int ni = 0; ni < 4; ++ni) {
            int gm = m0 + wm * 64 + mi * 16 + quad * 4;
            int gn = n0 + wn * 64 + ni * 16 + l16;
            float bv = bias[gn];
#pragma unroll
            for (int r = 0; r < 4; ++r)
                out[(size_t)(gm + r) * CC + gn] = acc[mi][ni][r] + bv;
        }
    }
}

extern "C" void kernel_launch(void* const* d_in, const int* in_sizes, int n_in,
                              void* d_out, int out_size, void* d_ws, size_t ws_size,
                              hipStream_t stream) {
    const float* x      = (const float*)d_in[0];
    const float* w_qkv  = (const float*)d_in[1];
    const float* b_qkv  = (const float*)d_in[2];
    const float* w_proj = (const float*)d_in[3];
    const float* b_proj = (const float*)d_in[4];
    float* out = (float*)d_out;
    char* ws = (char*)d_ws;

    short* xb     = (short*)(ws);                       // 8388608 B
    short* wqkvT  = (short*)(ws + 8388608);             // 6291456 B
    short* wprojT = (short*)(ws + 14680064);            // 2097152 B
    short* Qh     = (short*)(ws + 16777216);            // 8388608 B
    short* Kh     = (short*)(ws + 25165824);
    short* VhT    = (short*)(ws + 33554432);            // [H,64,T]
    short* Ob     = (short*)(ws + 41943040);
    // total 50331648 B (48 MB)

    k_cvt<<<4096, 256, 0, stream>>>(x, xb, TT * CC);
    k_transpose<<<dim3(N3C / 32, CC / 32), 256, 0, stream>>>(w_qkv, wqkvT, CC, N3C);
    k_transpose<<<dim3(CC / 32, CC / 32), 256, 0, stream>>>(w_proj, wprojT, CC, CC);
    k_gemm_qkv<<<dim3(N3C / 128, TT / 128), 256, 0, stream>>>(xb, wqkvT, b_qkv, Qh, Kh, VhT);
    k_attn<<<dim3(32, NHEAD), 256, 0, stream>>>(Qh, Kh, VhT, Ob);
    k_gemm_proj<<<dim3(CC / 128, TT / 128), 256, 0, stream>>>(Ob, wprojT, b_proj, out);
}

// Round 4
// 215.980 us; speedup vs baseline: 1.8504x; 1.0445x over previous
//
#include <hip/hip_runtime.h>
#include <hip/hip_bf16.h>

#define TT 4096
#define CC 1024
#define NHEAD 16
#define DH 64
#define N3C 3072

typedef __attribute__((ext_vector_type(8))) short short8;
typedef __attribute__((ext_vector_type(4))) float floatx4;

// Q pre-scale: 1/sqrt(64) * log2(e)  (softmax in exp2 domain, m=0 fixed)
#define QSCALE 0.18033688011112042f

__device__ __forceinline__ short f2bf(float f) {
    union { __hip_bfloat16 h; short s; } u;
    u.h = __float2bfloat16(f);
    return u.s;
}

// async global->LDS 16B per lane; LDS dest = wave-uniform base + lane*16
__device__ __forceinline__ void gload_lds16(const void* g, void* l) {
    __builtin_amdgcn_global_load_lds(
        (const __attribute__((address_space(1))) unsigned int*)(unsigned long long)g,
        (__attribute__((address_space(3))) unsigned int*)(unsigned int)(unsigned long long)l,
        16, 0, 0);
}

// pack two fp32 -> bf16x2 by truncation (1 v_perm)
__device__ __forceinline__ unsigned pk_trunc(float lo, float hi) {
    return __builtin_amdgcn_perm(__float_as_uint(hi), __float_as_uint(lo), 0x07060302u);
}

// ---------------- fused prep: cvt x->bf16, transpose both weights ----------------
__device__ __forceinline__ void tr_body(const float* __restrict__ in, short* __restrict__ out,
                                        int K, int N, int bx, int by, int tid, float (*tile)[33]) {
    int nt = bx * 32, kt = by * 32;
    int tx = tid & 31, ty = tid >> 5;
#pragma unroll
    for (int i = 0; i < 32; i += 8)
        tile[ty + i][tx] = in[(size_t)(kt + ty + i) * N + nt + tx];
    __syncthreads();
#pragma unroll
    for (int i = 0; i < 32; i += 8)
        out[(size_t)(nt + ty + i) * K + kt + tx] = f2bf(tile[tx][ty + i]);
}

__global__ void k_prep(const float* __restrict__ x, short* __restrict__ xb,
                       const float* __restrict__ w_qkv, short* __restrict__ wqkvT,
                       const float* __restrict__ w_proj, short* __restrict__ wprojT) {
    __shared__ float tile[32][33];
    int id = blockIdx.x;
    int tid = threadIdx.x;
    if (id < 4096) {
        int i = (id * 256 + tid) * 4;
        float4 v = *(const float4*)&x[i];
        short4 r;
        r.x = f2bf(v.x); r.y = f2bf(v.y); r.z = f2bf(v.z); r.w = f2bf(v.w);
        *(short4*)&xb[i] = r;
    } else if (id < 4096 + 3072) {
        int r = id - 4096;
        tr_body(w_qkv, wqkvT, CC, N3C, r % 96, r / 96, tid, tile);
    } else {
        int r = id - 7168;
        tr_body(w_proj, wprojT, CC, CC, r & 31, r >> 5, tid, tile);
    }
}

// ---------------- GEMM1: qkv = x @ w_qkv + b  (BK=64, two [128][32] sub-buffers) ----
// Q -> [H,T,64] pre-scaled; K -> [H,T,64]; V -> [H,64,T] (transposed)
__global__ __launch_bounds__(256) void k_gemm_qkv(const short* __restrict__ A,
                                                  const short* __restrict__ Bt,
                                                  const float* __restrict__ bias,
                                                  short* __restrict__ Q,
                                                  short* __restrict__ Kb,
                                                  short* __restrict__ Vtg) {
    const int m0 = blockIdx.y * 128;
    const int n0 = blockIdx.x * 128;
    __shared__ __attribute__((aligned(16))) short As[2][128 * 32];
    __shared__ __attribute__((aligned(16))) short Bs[2][128 * 32];
    const int tid = threadIdx.x;
    const int lane = tid & 63;
    const int w = tid >> 6;
    const int wm = w >> 1, wn = w & 1;
    const int quad = lane >> 4;
    const int l16 = lane & 15;

    const int r0 = tid >> 2, c0 = (tid & 3) * 8;
    // src pointers: [it][half]
    const short* pA[2][2]; const short* pB[2][2];
    short* lA[2][2]; short* lB[2][2];
#pragma unroll
    for (int it = 0; it < 2; ++it)
#pragma unroll
        for (int hh = 0; hh < 2; ++hh) {
            pA[it][hh] = A + (size_t)(m0 + it * 64 + r0) * CC + hh * 32 + c0;
            pB[it][hh] = Bt + (size_t)(n0 + it * 64 + r0) * CC + hh * 32 + c0;
            lA[it][hh] = &As[hh][(it * 256 + w * 64) * 8];
            lB[it][hh] = &Bs[hh][(it * 256 + w * 64) * 8];
        }

    floatx4 acc[4][4] = {};
    for (int kb = 0; kb < CC; kb += 64) {
        __syncthreads();
#pragma unroll
        for (int it = 0; it < 2; ++it)
#pragma unroll
            for (int hh = 0; hh < 2; ++hh) {
                gload_lds16(pA[it][hh] + kb, lA[it][hh]);
                gload_lds16(pB[it][hh] + kb, lB[it][hh]);
            }
        __syncthreads();
#pragma unroll
        for (int kk = 0; kk < 2; ++kk) {
            short8 af[4], bf[4];
#pragma unroll
            for (int mi = 0; mi < 4; ++mi)
                af[mi] = *(const short8*)&As[kk][(wm * 64 + mi * 16 + l16) * 32 + quad * 8];
#pragma unroll
            for (int ni = 0; ni < 4; ++ni)
                bf[ni] = *(const short8*)&Bs[kk][(wn * 64 + ni * 16 + l16) * 32 + quad * 8];
#pragma unroll
            for (int mi = 0; mi < 4; ++mi)
#pragma unroll
                for (int ni = 0; ni < 4; ++ni)
                    acc[mi][ni] = __builtin_amdgcn_mfma_f32_16x16x32_bf16(af[mi], bf[ni], acc[mi][ni], 0, 0, 0);
        }
    }
#pragma unroll
    for (int mi = 0; mi < 4; ++mi) {
#pragma unroll
        for (int ni = 0; ni < 4; ++ni) {
            int gm = m0 + wm * 64 + mi * 16 + quad * 4;
            int gn = n0 + wn * 64 + ni * 16 + l16;
            int which = gn >> 10;
            int cc = gn & 1023;
            int h = cc >> 6, d = cc & 63;
            float bv = bias[gn];
            if (which == 0) {
#pragma unroll
                for (int r = 0; r < 4; ++r) {
                    float v = (acc[mi][ni][r] + bv) * QSCALE;
                    Q[((size_t)h * TT + (gm + r)) * DH + d] = f2bf(v);
                }
            } else if (which == 1) {
#pragma unroll
                for (int r = 0; r < 4; ++r) {
                    float v = acc[mi][ni][r] + bv;
                    Kb[((size_t)h * TT + (gm + r)) * DH + d] = f2bf(v);
                }
            } else {
                short4 vv;
                vv.x = f2bf(acc[mi][ni][0] + bv);
                vv.y = f2bf(acc[mi][ni][1] + bv);
                vv.z = f2bf(acc[mi][ni][2] + bv);
                vv.w = f2bf(acc[mi][ni][3] + bv);
                *(short4*)&Vtg[((size_t)h * DH + d) * TT + gm] = vv;
            }
        }
    }
}

// ---------------- flash attention v3 ----------------
// K & V fragments direct from global (no LDS, no DMA); only P round-trips LDS.
// S^T k-strip per wave; PV d-strip per wave; Ps double-buffered -> 1 barrier/iter.
// grid (h, pair): same-head blocks pinned to one XCD for K/V L2 residency.
__global__ __launch_bounds__(256) void k_attn(const short* __restrict__ Qh,
                                              const short* __restrict__ Kh,
                                              const short* __restrict__ VhT,
                                              short* __restrict__ Ob) {
    const int h = blockIdx.x;
    const int pair = blockIdx.y;    // 0..31
    const int tid = threadIdx.x, lane = tid & 63, w = tid >> 6;
    const int quad = lane >> 4, l16 = lane & 15;

    __shared__ __attribute__((aligned(16))) short Ps[2][64 * 136];
    __shared__ float wl[4][64];
    __shared__ float lsum[64];

    const short* Qp = Qh + (size_t)h * TT * DH;
    const short* Kp = Kh + (size_t)h * TT * DH;
    const short* Vp = VhT + (size_t)h * DH * TT;

    int buf = 0;

#pragma unroll 1
    for (int half = 0; half < 2; ++half) {
        const int qi = half ? (63 - pair) : pair;
        const int q0 = qi * 64;
        const int nk = (qi >> 1) + 1;

        short8 aq[4][2];
#pragma unroll
        for (int qg = 0; qg < 4; ++qg)
#pragma unroll
            for (int s = 0; s < 2; ++s)
                aq[qg][s] = *(const short8*)&Qp[(size_t)(q0 + qg * 16 + l16) * DH + s * 32 + quad * 8];

        floatx4 accO[4] = {};
        float l_part[4] = {0.f, 0.f, 0.f, 0.f};

        for (int ki = 0; ki < nk; ++ki) {
            const int k0 = ki * 128;
            const bool masked = (ki == nk - 1);

            // K fragments: wave's k-strip [k0+w*32, +32)
            short8 kf[2][2];
#pragma unroll
            for (int mi = 0; mi < 2; ++mi)
#pragma unroll
                for (int s = 0; s < 2; ++s)
                    kf[mi][s] = *(const short8*)&Kp[(size_t)(k0 + w * 32 + mi * 16 + l16) * DH + s * 32 + quad * 8];

            // S^T strips: D[k][q], lane: k = w*32+mi*16+quad*4+r, q = qg*16+l16
            floatx4 accS[2][4] = {};
#pragma unroll
            for (int mi = 0; mi < 2; ++mi)
#pragma unroll
                for (int s = 0; s < 2; ++s)
#pragma unroll
                    for (int qg = 0; qg < 4; ++qg)
                        accS[mi][qg] = __builtin_amdgcn_mfma_f32_16x16x32_bf16(kf[mi][s], aq[qg][s], accS[mi][qg], 0, 0, 0);

            // softmax (m=0, exp2 domain) + pack -> Ps
            short* Pb = &Ps[buf][0];
#pragma unroll
            for (int mi = 0; mi < 2; ++mi) {
                const int kbase = k0 + w * 32 + mi * 16 + quad * 4;
#pragma unroll
                for (int qg = 0; qg < 4; ++qg) {
                    float p[4];
#pragma unroll
                    for (int r = 0; r < 4; ++r) {
                        float e = __builtin_amdgcn_exp2f(accS[mi][qg][r]);
                        if (masked)
                            e = (kbase + r <= q0 + qg * 16 + l16) ? e : 0.f;
                        p[r] = e;
                        l_part[qg] += e;
                    }
                    uint2 pk;
                    pk.x = pk_trunc(p[0], p[1]);
                    pk.y = pk_trunc(p[2], p[3]);
                    *(uint2*)&Pb[(qg * 16 + l16) * 136 + w * 32 + mi * 16 + quad * 4] = pk;
                }
            }

            // V fragments (d-strip [w*16,+16)) — issue before barrier to hide latency
            short8 vf[4];
#pragma unroll
            for (int ks = 0; ks < 4; ++ks)
                vf[ks] = *(const short8*)&Vp[(size_t)(w * 16 + l16) * TT + k0 + ks * 32 + quad * 8];

            __syncthreads();   // Ps[buf] visible (lgkm only — no DMA in flight)

            // O[q][d-strip] += P V : A = P[q][k] frags, B = V frags
#pragma unroll
            for (int qg = 0; qg < 4; ++qg)
#pragma unroll
                for (int ks = 0; ks < 4; ++ks) {
                    short8 ap = *(const short8*)&Pb[(qg * 16 + l16) * 136 + ks * 32 + quad * 8];
                    accO[qg] = __builtin_amdgcn_mfma_f32_16x16x32_bf16(ap, vf[ks], accO[qg], 0, 0, 0);
                }
            buf ^= 1;
        }

        // reduce l: lane holds partials for q = qg*16+l16 (over its 8 k-rows)
#pragma unroll
        for (int qg = 0; qg < 4; ++qg) {
            float lr = l_part[qg];
            lr += __shfl_xor(lr, 16, 64);
            lr += __shfl_xor(lr, 32, 64);
            if (lane < 16) wl[w][qg * 16 + lane] = lr;
        }
        __syncthreads();
        if (tid < 64) lsum[tid] = wl[0][tid] + wl[1][tid] + wl[2][tid] + wl[3][tid];
        __syncthreads();

        // epilogue: lane holds O[q = qg*16+quad*4+r][d = w*16+l16]
#pragma unroll
        for (int qg = 0; qg < 4; ++qg) {
#pragma unroll
            for (int r = 0; r < 4; ++r) {
                int q = qg * 16 + quad * 4 + r;
                float o = accO[qg][r] / lsum[q];
                Ob[(size_t)(q0 + q) * CC + h * DH + w * 16 + l16] = f2bf(o);
            }
        }
    }
}

// ---------------- GEMM2: out = Ob @ w_proj + b (fp32 out, BK=64) ----------------
__global__ __launch_bounds__(256) void k_gemm_proj(const short* __restrict__ A,
                                                   const short* __restrict__ Bt,
                                                   const float* __restrict__ bias,
                                                   float* __restrict__ out) {
    const int m0 = blockIdx.y * 128;
    const int n0 = blockIdx.x * 128;
    __shared__ __attribute__((aligned(16))) short As[2][128 * 32];
    __shared__ __attribute__((aligned(16))) short Bs[2][128 * 32];
    const int tid = threadIdx.x;
    const int lane = tid & 63;
    const int w = tid >> 6;
    const int wm = w >> 1, wn = w & 1;
    const int quad = lane >> 4;
    const int l16 = lane & 15;

    const int r0 = tid >> 2, c0 = (tid & 3) * 8;
    const short* pA[2][2]; const short* pB[2][2];
    short* lA[2][2]; short* lB[2][2];
#pragma unroll
    for (int it = 0; it < 2; ++it)
#pragma unroll
        for (int hh = 0; hh < 2; ++hh) {
            pA[it][hh] = A + (size_t)(m0 + it * 64 + r0) * CC + hh * 32 + c0;
            pB[it][hh] = Bt + (size_t)(n0 + it * 64 + r0) * CC + hh * 32 + c0;
            lA[it][hh] = &As[hh][(it * 256 + w * 64) * 8];
            lB[it][hh] = &Bs[hh][(it * 256 + w * 64) * 8];
        }

    floatx4 acc[4][4] = {};
    for (int kb = 0; kb < CC; kb += 64) {
        __syncthreads();
#pragma unroll
        for (int it = 0; it < 2; ++it)
#pragma unroll
            for (int hh = 0; hh < 2; ++hh) {
                gload_lds16(pA[it][hh] + kb, lA[it][hh]);
                gload_lds16(pB[it][hh] + kb, lB[it][hh]);
            }
        __syncthreads();
#pragma unroll
        for (int kk = 0; kk < 2; ++kk) {
            short8 af[4], bf[4];
#pragma unroll
            for (int mi = 0; mi < 4; ++mi)
                af[mi] = *(const short8*)&As[kk][(wm * 64 + mi * 16 + l16) * 32 + quad * 8];
#pragma unroll
            for (int ni = 0; ni < 4; ++ni)
                bf[ni] = *(const short8*)&Bs[kk][(wn * 64 + ni * 16 + l16) * 32 + quad * 8];
#pragma unroll
            for (int mi = 0; mi < 4; ++mi)
#pragma unroll
                for (int ni = 0; ni < 4; ++ni)
                    acc[mi][ni] = __builtin_amdgcn_mfma_f32_16x16x32_bf16(af[mi], bf[ni], acc[mi][ni], 0, 0, 0);
        }
    }
#pragma unroll
    for (int mi = 0; mi < 4; ++mi) {
#pragma unroll
        for (int ni = 0; ni < 4; ++ni) {
            int gm = m0 + wm * 64 + mi * 16 + quad * 4;
            int gn = n0 + wn * 64 + ni * 16 + l16;
            float bv = bias[gn];
#pragma unroll
            for (int r = 0; r < 4; ++r)
                out[(size_t)(gm + r) * CC + gn] = acc[mi][ni][r] + bv;
        }
    }
}

extern "C" void kernel_launch(void* const* d_in, const int* in_sizes, int n_in,
                              void* d_out, int out_size, void* d_ws, size_t ws_size,
                              hipStream_t stream) {
    const float* x      = (const float*)d_in[0];
    const float* w_qkv  = (const float*)d_in[1];
    const float* b_qkv  = (const float*)d_in[2];
    const float* w_proj = (const float*)d_in[3];
    const float* b_proj = (const float*)d_in[4];
    float* out = (float*)d_out;
    char* ws = (char*)d_ws;

    short* xb     = (short*)(ws);                       // 8388608 B
    short* wqkvT  = (short*)(ws + 8388608);             // 6291456 B
    short* wprojT = (short*)(ws + 14680064);            // 2097152 B
    short* Qh     = (short*)(ws + 16777216);            // 8388608 B
    short* Kh     = (short*)(ws + 25165824);
    short* VhT    = (short*)(ws + 33554432);            // [H,64,T]
    short* Ob     = (short*)(ws + 41943040);
    // total 50331648 B (48 MB)

    k_prep<<<8192, 256, 0, stream>>>(x, xb, w_qkv, wqkvT, w_proj, wprojT);
    k_gemm_qkv<<<dim3(N3C / 128, TT / 128), 256, 0, stream>>>(xb, wqkvT, b_qkv, Qh, Kh, VhT);
    k_attn<<<dim3(NHEAD, 32), 256, 0, stream>>>(Qh, Kh, VhT, Ob);
    k_gemm_proj<<<dim3(CC / 128, TT / 128), 256, 0, stream>>>(Ob, wprojT, b_proj, out);
}